// Round 5
// baseline (171.163 us; speedup 1.0000x reference)
//
#include <hip/hip_runtime.h>

// Problem: B=256, T=256 trees, E=64, H=4.
// out[b,t,e] = sum_{j!=t,h} relu(x[b,j,:]·W1[t,j,:,h] + b1[t,j,h]) * W2[t,pos(j)*4+h,e] + b2[t,e]
//
// R5: two-phase via workspace.
//   ws layout: xT bf16 [j][b][e] (8.4MB) | W2T bf16 [t][e][1024k] (33.6MB) | H bf16 [i][b][j][h] (134MB/NS)
//   phaseA (per j): H = relu(W1_j^T x_j + b1)  -- x in regs, W1 thru LDS dbuf, 8B/lane H-stores
//                   (j-octet XCD swizzle so L2 merges 8x8B into 64B lines)
//   phaseB (per tree,b-half): out = H2 · W2T + b2 -- persistent-acc GEMM, K=1020 in 16 chunks
// Fallback (small ws): R4 monolithic fused kernel.

namespace {

constexpr int T_ = 256;
constexpr int E_ = 64;
constexpr int K2_ = 1020;           // (T-1)*H

typedef float  f32x4  __attribute__((ext_vector_type(4)));
typedef short  bf16x8 __attribute__((ext_vector_type(8)));
typedef unsigned short u16x4 __attribute__((ext_vector_type(4)));

__device__ inline unsigned short f2b(float f) {
    union { float f; unsigned u; } v; v.f = f;
    unsigned r = v.u + 0x7fffu + ((v.u >> 16) & 1u);   // RNE bf16
    return (unsigned short)(r >> 16);
}

__device__ inline bf16x8 pack8(f32x4 a, f32x4 b) {
    bf16x8 r;
    r[0] = (short)f2b(a[0]); r[1] = (short)f2b(a[1]);
    r[2] = (short)f2b(a[2]); r[3] = (short)f2b(a[3]);
    r[4] = (short)f2b(b[0]); r[5] = (short)f2b(b[1]);
    r[6] = (short)f2b(b[2]); r[7] = (short)f2b(b[3]);
    return r;
}

// R4 fallback LDS geometry
constexpr int JC = 4;
constexpr int CHUNKS = 16;
constexpr int W1_ROW   = 72;
constexpr int W1_PLANE = 32 * W1_ROW + 8;
constexpr int PB_ROW   = 24;
constexpr int PB_PLANE = 64 * PB_ROW + 8;
constexpr int W2_ROW   = 16;
constexpr int W2_PLANE = 64 * W2_ROW + 8;

} // namespace

// ======================= shared helpers =======================

// x[b][j][e] f32 -> xT[j][b][e] bf16 (used by both paths)
__global__ __launch_bounds__(256) void xcast_kernel(
    const float* __restrict__ x, unsigned short* __restrict__ xT)
{
    const int g     = blockIdx.x * 256 + threadIdx.x;   // 262,144
    const int part  = g & 3;                            // 16 e's each
    const int rowid = g >> 2;                           // = b*256 + j
    const int b = rowid >> 8, j = rowid & 255;
    const float* src = x + (size_t)rowid * E_ + part * 16;
    f32x4 v0 = *(const f32x4*)(src);
    f32x4 v1 = *(const f32x4*)(src + 4);
    f32x4 v2 = *(const f32x4*)(src + 8);
    f32x4 v3 = *(const f32x4*)(src + 12);
    unsigned short* dst = xT + ((size_t)j * 256 + b) * E_ + part * 16;
    *(bf16x8*)(dst)     = pack8(v0, v1);
    *(bf16x8*)(dst + 8) = pack8(v2, v3);
}

// out[b,t,e] = b2[t,e] (fallback path only)
__global__ __launch_bounds__(256) void init_out_kernel(
    const float* __restrict__ b2, float* __restrict__ out)
{
    const int idx = blockIdx.x * 256 + threadIdx.x;
    ((f32x4*)out)[idx] = ((const f32x4*)b2)[idx & 4095];
}

// ======================= two-phase path =======================

// W2[t][k][e] f32 -> W2T[t][e][k] bf16 (k-stride padded to 1024)
__global__ __launch_bounds__(512, 2) void w2t_kernel(
    const float* __restrict__ W2, unsigned short* __restrict__ W2T)
{
    __shared__ __align__(16) unsigned short sT[64][136];
    const int bid = blockIdx.x;
    const int t = bid >> 3, kb = bid & 7;               // 8 k-blocks of 128
    const int tid = threadIdx.x;
    {
        const int k  = tid >> 2;            // 0..127
        const int e0 = (tid & 3) << 4;      // 0,16,32,48
        const int kg = kb * 128 + k;
        f32x4 v0 = {0,0,0,0}, v1 = {0,0,0,0}, v2 = {0,0,0,0}, v3 = {0,0,0,0};
        if (kg < K2_) {
            const float* src = W2 + ((size_t)t * K2_ + kg) * E_ + e0;
            v0 = *(const f32x4*)(src);
            v1 = *(const f32x4*)(src + 4);
            v2 = *(const f32x4*)(src + 8);
            v3 = *(const f32x4*)(src + 12);
        }
        #pragma unroll
        for (int m = 0; m < 4; ++m) {
            sT[e0 + m     ][k] = f2b(v0[m]);
            sT[e0 + 4 + m ][k] = f2b(v1[m]);
            sT[e0 + 8 + m ][k] = f2b(v2[m]);
            sT[e0 + 12 + m][k] = f2b(v3[m]);
        }
    }
    __syncthreads();
    {
        const int e  = tid >> 3;            // 0..63
        const int ko = tid & 7;             // 16 k's each
        const unsigned short* srow = &sT[e][ko * 16];
        bf16x8 a = *(const bf16x8*)(srow);
        bf16x8 b = *(const bf16x8*)(srow + 8);
        unsigned short* dst = W2T + ((size_t)t * 64 + e) * 1024 + kb * 128 + ko * 16;
        *(bf16x8*)(dst)     = a;
        *(bf16x8*)(dst + 8) = b;
    }
}

// Phase A: block = one j. H[iR][b][j][h] = relu(W1^T x + b1) for iR in [0, NC*16).
// A-operand = W1 rows (m = i_loc*4+h) from LDS, B-operand = x cols (n = b) in regs.
__global__ __launch_bounds__(512, 1) void phaseA_kernel(
    const unsigned short* __restrict__ xT,  // [j][b][e]
    const float* __restrict__ W1,           // [256][256][64][4]
    const float* __restrict__ b1,           // [256][256][4]
    unsigned short* __restrict__ H,         // [TS][256 b][256 j][4 h]
    int i_base, int NC)
{
    __shared__ __align__(16) unsigned short sW1[2][64][72];   // [m=4i+h][e], 18.4KB

    const int bid = blockIdx.x;
    // j-octet XCD swizzle: XCD x (= bid%8) gets j in [32x, 32x+32) -> octets co-resident.
    const int j = ((bid & 7) << 5) | (bid >> 3);
    const int tid = threadIdx.x;
    const int w = tid >> 6, lane = tid & 63, r16 = lane & 15, kg = lane >> 4;

    // x fragments (B operand), loaded once per block
    bf16x8 xb[2][2];
    #pragma unroll
    for (int nt = 0; nt < 2; ++nt) {
        const int b = w * 32 + nt * 16 + r16;
        const unsigned short* xr = xT + ((size_t)j * 256 + b) * 64 + kg * 8;
        xb[nt][0] = *(const bf16x8*)(xr);
        xb[nt][1] = *(const bf16x8*)(xr + 32);
    }

    auto stage = [&](int nc, int pb) {
        const int i_loc = tid >> 5;          // 0..15
        const int part  = tid & 31;          // 8 consecutive (e,h) each
        const int I = i_base + nc * 16 + i_loc;
        const float* src = W1 + (((size_t)I * 256 + j) << 8) + part * 8;
        f32x4 v0 = *(const f32x4*)(src);
        f32x4 v1 = *(const f32x4*)(src + 4);
        #pragma unroll
        for (int s = 0; s < 8; ++s) {
            const int ff = part * 8 + s;                 // ff = e*4 + h
            const float vv = (s < 4) ? v0[s & 3] : v1[s & 3];
            sW1[pb][(i_loc << 2) | (ff & 3)][ff >> 2] = f2b(vv);
        }
    };

    stage(0, 0);
    __syncthreads();

    for (int nc = 0; nc < NC; ++nc) {
        const int pb = nc & 1;
        if (nc + 1 < NC) stage(nc + 1, pb ^ 1);   // prefetch overlaps compute

        f32x4 acc[4][2];
        #pragma unroll
        for (int mt = 0; mt < 4; ++mt)
            #pragma unroll
            for (int nt = 0; nt < 2; ++nt)
                acc[mt][nt] = (f32x4){0.f, 0.f, 0.f, 0.f};

        #pragma unroll
        for (int mt = 0; mt < 4; ++mt) {
            const unsigned short* ar = &sW1[pb][mt * 16 + r16][0];
            bf16x8 a0 = *(const bf16x8*)(ar + kg * 8);
            bf16x8 a1 = *(const bf16x8*)(ar + 32 + kg * 8);
            #pragma unroll
            for (int nt = 0; nt < 2; ++nt) {
                acc[mt][nt] = __builtin_amdgcn_mfma_f32_16x16x32_bf16(a0, xb[nt][0], acc[mt][nt], 0, 0, 0);
                acc[mt][nt] = __builtin_amdgcn_mfma_f32_16x16x32_bf16(a1, xb[nt][1], acc[mt][nt], 0, 0, 0);
            }
        }

        // epilogue: lane holds (i fixed, h=0..3) per tile -> 8B contiguous H store
        #pragma unroll
        for (int mt = 0; mt < 4; ++mt) {
            const int iR = nc * 16 + mt * 4 + kg;
            const int Ig = i_base + iR;
            f32x4 bias = *(const f32x4*)(b1 + (((size_t)Ig << 8) + j) * 4);
            #pragma unroll
            for (int nt = 0; nt < 2; ++nt) {
                const int b = w * 32 + nt * 16 + r16;
                float v0 = acc[mt][nt][0] + bias[0]; v0 = v0 > 0.f ? v0 : 0.f;
                float v1 = acc[mt][nt][1] + bias[1]; v1 = v1 > 0.f ? v1 : 0.f;
                float v2 = acc[mt][nt][2] + bias[2]; v2 = v2 > 0.f ? v2 : 0.f;
                float v3 = acc[mt][nt][3] + bias[3]; v3 = v3 > 0.f ? v3 : 0.f;
                uint2 pk;
                pk.x = (unsigned)f2b(v0) | ((unsigned)f2b(v1) << 16);
                pk.y = (unsigned)f2b(v2) | ((unsigned)f2b(v3) << 16);
                *(uint2*)(H + ((size_t)iR << 18) + ((size_t)b << 10) + (j << 2)) = pk;
            }
        }
        __syncthreads();
    }
}

// Phase B: block = (tree, b-half). out[b][t][:] = sum_k H2[b][k] W2T[t][:][k] + b2.
// M=128, N=64, K=1020 in 16 chunks of 64 (16 j's); persistent acc.
__global__ __launch_bounds__(512, 4) void phaseB_kernel(
    const unsigned short* __restrict__ H,    // [TS][256][256][4]
    const unsigned short* __restrict__ W2T,  // [256][64][1024]
    const float* __restrict__ b2,            // [256][64]
    float* __restrict__ out,                 // [256][256][64]
    int i_base)
{
    __shared__ __align__(16) unsigned short sA[2][128][72];  // [b][kk] 36.9KB
    __shared__ __align__(16) unsigned short sB[2][64][72];   // [e][kk] 18.4KB

    const int bid = blockIdx.x;
    const int t_loc = bid >> 1;
    const int t  = i_base + t_loc;
    const int b0 = (bid & 1) << 7;
    const int tid = threadIdx.x;
    const int w = tid >> 6, lane = tid & 63, r16 = lane & 15, kg = lane >> 4;

    auto stageA = [&](int c, int pb) {
        const int b = tid >> 2;             // 0..127
        const int q = tid & 3;              // 32B each
        const unsigned short* src =
            H + ((size_t)t_loc << 18) + ((size_t)(b0 + b) << 10) + (c << 6) + (q << 4);
        bf16x8 v0 = *(const bf16x8*)(src);
        bf16x8 v1 = *(const bf16x8*)(src + 8);
        *(bf16x8*)&sA[pb][b][(q << 4)]     = v0;
        *(bf16x8*)&sA[pb][b][(q << 4) + 8] = v1;
    };
    auto stageB = [&](int c, int pb) {
        const int e   = tid >> 3;           // 0..63
        const int grp = tid & 7;            // 2 j's each
        const unsigned short* base = W2T + ((size_t)t * 64 + e) * 1024;
        #pragma unroll
        for (int js = 0; js < 2; ++js) {
            const int jj = grp * 2 + js;    // 0..15
            const int j  = c * 16 + jj;
            u16x4 v;
            if (j == t) {
                v = (u16x4){0, 0, 0, 0};
            } else {
                const int ks = ((j < t) ? j : j - 1) << 2;
                v = *(const u16x4*)(base + ks);
            }
            *(u16x4*)&sB[pb][e][jj << 2] = v;
        }
    };

    stageA(0, 0); stageB(0, 0);
    __syncthreads();

    f32x4 acc[4];
    #pragma unroll
    for (int nt = 0; nt < 4; ++nt) acc[nt] = (f32x4){0.f, 0.f, 0.f, 0.f};

    for (int c = 0; c < 16; ++c) {
        const int pb = c & 1;
        if (c + 1 < 16) { stageA(c + 1, pb ^ 1); stageB(c + 1, pb ^ 1); }

        const unsigned short* ar = &sA[pb][w * 16 + r16][0];
        bf16x8 a0 = *(const bf16x8*)(ar + kg * 8);
        bf16x8 a1 = *(const bf16x8*)(ar + 32 + kg * 8);
        #pragma unroll
        for (int nt = 0; nt < 4; ++nt) {
            const unsigned short* br = &sB[pb][nt * 16 + r16][0];
            bf16x8 bb0 = *(const bf16x8*)(br + kg * 8);
            bf16x8 bb1 = *(const bf16x8*)(br + 32 + kg * 8);
            acc[nt] = __builtin_amdgcn_mfma_f32_16x16x32_bf16(a0, bb0, acc[nt], 0, 0, 0);
            acc[nt] = __builtin_amdgcn_mfma_f32_16x16x32_bf16(a1, bb1, acc[nt], 0, 0, 0);
        }
        __syncthreads();
    }

    #pragma unroll
    for (int nt = 0; nt < 4; ++nt) {
        const int e = nt * 16 + r16;
        const float bias = b2[(t << 6) + e];
        #pragma unroll
        for (int r = 0; r < 4; ++r) {
            const int b = b0 + w * 16 + kg * 4 + r;
            out[((size_t)b << 14) + (t << 6) + e] = acc[nt][r] + bias;
        }
    }
}

// ======================= fallback: R4 monolithic fused kernel =======================

template <bool XBF>
__global__ __launch_bounds__(512, 4) void fused_forest_kernel(
    const void*  __restrict__ xv,
    const float* __restrict__ W1,
    const float* __restrict__ b1,
    const float* __restrict__ W2,
    float* __restrict__ out)
{
    __shared__ __align__(16) unsigned short sW1[4 * W1_PLANE];
    __shared__ __align__(16) unsigned short sPB[8 * PB_PLANE];
    __shared__ __align__(16) unsigned short sW2[2][8 * W2_PLANE];
    __shared__ __align__(16) float sB1[4][32];

    const int bid = blockIdx.x;
    const int xcd = bid & 7;
    const int rr  = bid >> 3;
    const int tgl = rr >> 4;
    const int bg  = (rr >> 2) & 3;
    const int jg  = rr & 3;
    const int tg  = tgl * 8 + xcd;
    const int i0  = tg << 3;
    const int b0  = bg << 6;
    const int j0g = jg << 6;

    const int tid  = threadIdx.x;
    const int w    = tid >> 6;
    const int lane = tid & 63;
    const int r16  = lane & 15;
    const int kg   = lane >> 4;
    const int bt   = w & 3;
    const int mh   = w >> 2;

    f32x4 acc[4][4];
    #pragma unroll
    for (int mt = 0; mt < 4; ++mt)
        #pragma unroll
        for (int nt = 0; nt < 4; ++nt)
            acc[mt][nt] = (f32x4){0.f, 0.f, 0.f, 0.f};

    auto stage = [&](int c, int pb) {
        const int j0 = j0g + c * JC;
        if (tid < 128) {
            const int jj = tid >> 5, ih = tid & 31;
            sB1[jj][ih] = b1[((i0 + (ih >> 2)) * T_ + (j0 + jj)) * 4 + (ih & 3)];
        }
        {
            const float* src = W1 + (((size_t)(i0 + w) * T_ + (j0 + kg)) * E_) * 4 + r16 * 16;
            f32x4 v0 = *(const f32x4*)(src);
            f32x4 v1 = *(const f32x4*)(src + 4);
            f32x4 v2 = *(const f32x4*)(src + 8);
            f32x4 v3 = *(const f32x4*)(src + 12);
            #pragma unroll
            for (int h = 0; h < 4; ++h) {
                u16x4 pk = (u16x4){f2b(v0[h]), f2b(v1[h]), f2b(v2[h]), f2b(v3[h])};
                *(u16x4*)&sW1[kg * W1_PLANE + (w * 4 + h) * W1_ROW + r16 * 4] = pk;
            }
        }
        {
            const int kk   = lane >> 2;
            const int e0   = (lane & 3) * 16;
            const int tabs = i0 + w;
            const int j    = j0 + (kk >> 2);
            unsigned short* dst = &sW2[pb][w * W2_PLANE + kk];
            if (j == tabs) {
                #pragma unroll
                for (int q = 0; q < 16; ++q) dst[(e0 + q) * W2_ROW] = 0;
            } else {
                const int ksrc = ((j < tabs) ? j : j - 1) * 4 + (kk & 3);
                const float* src = W2 + ((size_t)tabs * K2_ + ksrc) * E_ + e0;
                f32x4 v0 = *(const f32x4*)(src);
                f32x4 v1 = *(const f32x4*)(src + 4);
                f32x4 v2 = *(const f32x4*)(src + 8);
                f32x4 v3 = *(const f32x4*)(src + 12);
                #pragma unroll
                for (int q = 0; q < 4; ++q) {
                    dst[(e0 + q)      * W2_ROW] = f2b(v0[q]);
                    dst[(e0 + 4 + q)  * W2_ROW] = f2b(v1[q]);
                    dst[(e0 + 8 + q)  * W2_ROW] = f2b(v2[q]);
                    dst[(e0 + 12 + q) * W2_ROW] = f2b(v3[q]);
                }
            }
        }
    };

    stage(0, 0);
    __syncthreads();

    const int brow = b0 + bt * 16 + r16;

    for (int c = 0; c < CHUNKS; ++c) {
        const int j0 = j0g + c * JC;
        #pragma unroll
        for (int jj = 0; jj < JC; ++jj) {
            bf16x8 xa, xc;
            if (XBF) {
                const unsigned short* xr =
                    (const unsigned short*)xv + ((size_t)(j0 + jj) * 256 + brow) * E_;
                xa = *(const bf16x8*)(xr + kg * 8);
                xc = *(const bf16x8*)(xr + 32 + kg * 8);
            } else {
                const float* xr = (const float*)xv + ((size_t)brow * T_ + (j0 + jj)) * E_ + kg * 8;
                xa = pack8(*(const f32x4*)xr, *(const f32x4*)(xr + 4));
                xc = pack8(*(const f32x4*)(xr + 32), *(const f32x4*)(xr + 36));
            }
            const unsigned short* wr = &sW1[jj * W1_PLANE + (mh * 16 + r16) * W1_ROW];
            bf16x8 wa = *(const bf16x8*)(wr + kg * 8);
            bf16x8 wc = *(const bf16x8*)(wr + 32 + kg * 8);
            f32x4 cf = (f32x4){0.f, 0.f, 0.f, 0.f};
            cf = __builtin_amdgcn_mfma_f32_16x16x32_bf16(wa, xa, cf, 0, 0, 0);
            cf = __builtin_amdgcn_mfma_f32_16x16x32_bf16(wc, xc, cf, 0, 0, 0);
            const int i = mh * 4 + kg;
            f32x4 bias = *(const f32x4*)&sB1[jj][i * 4];
            #pragma unroll
            for (int r = 0; r < 4; ++r) {
                float vv = cf[r] + bias[r];
                cf[r] = vv > 0.f ? vv : 0.f;
            }
            unsigned p0 = (unsigned)f2b(cf[0]) | ((unsigned)f2b(cf[1]) << 16);
            unsigned p1 = (unsigned)f2b(cf[2]) | ((unsigned)f2b(cf[3]) << 16);
            uint2 pk; pk.x = p0; pk.y = p1;
            *(uint2*)&sPB[i * PB_PLANE + (bt * 16 + r16) * PB_ROW + jj * 4] = pk;
        }
        __syncthreads();

        {
            const bf16x8 z = (bf16x8){0,0,0,0,0,0,0,0};
            const bool lo = (kg < 2);
            bf16x8 a2[4], bb[4];
            #pragma unroll
            for (int mt = 0; mt < 4; ++mt)
                a2[mt] = lo ? *(const bf16x8*)&sPB[w * PB_PLANE + (mt * 16 + r16) * PB_ROW + kg * 8] : z;
            #pragma unroll
            for (int nt = 0; nt < 4; ++nt)
                bb[nt] = lo ? *(const bf16x8*)&sW2[c & 1][w * W2_PLANE + (nt * 16 + r16) * W2_ROW + kg * 8] : z;
            #pragma unroll
            for (int mt = 0; mt < 4; ++mt)
                #pragma unroll
                for (int nt = 0; nt < 4; ++nt)
                    acc[mt][nt] = __builtin_amdgcn_mfma_f32_16x16x32_bf16(
                        a2[mt], bb[nt], acc[mt][nt], 0, 0, 0);
        }

        if (c + 1 < CHUNKS) stage(c + 1, (c + 1) & 1);
        __syncthreads();
    }

    const int tabs = i0 + w;
    #pragma unroll
    for (int mt = 0; mt < 4; ++mt) {
        const int b = b0 + mt * 16 + kg * 4;
        #pragma unroll
        for (int nt = 0; nt < 4; ++nt) {
            const int e = nt * 16 + r16;
            #pragma unroll
            for (int r = 0; r < 4; ++r)
                unsafeAtomicAdd(&out[((size_t)(b + r) * T_ + tabs) * E_ + e],
                                acc[mt][nt][r]);
        }
    }
}

// ======================= host =======================

extern "C" void kernel_launch(void* const* d_in, const int* in_sizes, int n_in,
                              void* d_out, int out_size, void* d_ws, size_t ws_size,
                              hipStream_t stream) {
    const float* x  = (const float*)d_in[0];
    const float* W1 = (const float*)d_in[1];
    const float* b1 = (const float*)d_in[2];
    const float* W2 = (const float*)d_in[3];
    const float* b2 = (const float*)d_in[4];
    float* out = (float*)d_out;
    (void)in_sizes; (void)n_in; (void)out_size;

    const size_t xT_b   = 8388608ull;     // 256*256*64*2
    const size_t w2t_b  = 33554432ull;    // 256*64*1024*2
    const size_t H_full = 134217728ull;   // 256*256*256*4*2

    int NS = 0;
    if (d_ws) {
        const int cands[4] = {1, 2, 4, 8};
        for (int ci = 0; ci < 4; ++ci) {
            if (ws_size >= xT_b + w2t_b + H_full / cands[ci]) { NS = cands[ci]; break; }
        }
    }

    if (NS) {
        unsigned short* xT  = (unsigned short*)d_ws;
        unsigned short* W2T = (unsigned short*)((char*)d_ws + xT_b);
        unsigned short* H   = (unsigned short*)((char*)d_ws + xT_b + w2t_b);

        hipLaunchKernelGGL(xcast_kernel, dim3(1024), dim3(256), 0, stream, x, xT);
        hipLaunchKernelGGL(w2t_kernel, dim3(2048), dim3(512), 0, stream, W2, W2T);

        const int TS = 256 / NS;
        for (int s = 0; s < NS; ++s) {
            hipLaunchKernelGGL(phaseA_kernel, dim3(256), dim3(512), 0, stream,
                               xT, W1, b1, H, s * TS, TS / 16);
            hipLaunchKernelGGL(phaseB_kernel, dim3(TS * 2), dim3(512), 0, stream,
                               H, W2T, b2, out, s * TS);
        }
    } else {
        const bool xbf = d_ws && ws_size >= xT_b;
        hipLaunchKernelGGL(init_out_kernel, dim3(4096), dim3(256), 0, stream, b2, out);
        if (xbf) {
            hipLaunchKernelGGL(xcast_kernel, dim3(1024), dim3(256), 0, stream,
                               x, (unsigned short*)d_ws);
            hipLaunchKernelGGL(fused_forest_kernel<true>, dim3(512), dim3(512), 0, stream,
                               (const void*)d_ws, W1, b1, W2, out);
        } else {
            hipLaunchKernelGGL(fused_forest_kernel<false>, dim3(512), dim3(512), 0, stream,
                               (const void*)x, W1, b1, W2, out);
        }
    }
}

// Round 6
// 153.972 us; speedup vs baseline: 1.1117x; 1.1117x over previous
//
#include <hip/hip_runtime.h>

// Problem: B=256, T=256 trees, E=64, H=4.
// out[b,t,e] = sum_{j!=t,h} relu(x[b,j,:]·W1[t,j,:,h] + b1[t,j,h]) * W2[t,pos(j)*4+h,e] + b2[t,e]
//
// R6: phaseA rebuilt to kill store-request fragmentation.
//   phaseA2 block = (j-octet, i-tile of 16, b-half of 128): per-j MFMAs -> LDS tile
//   sH[4i][128b][32k] -> coalesced 64B/row global flush (full-sector requests).
//   x frags register-resident; W1 staged via vectorized b128 LDS writes.
//   phaseB / w2t / xcast unchanged from R5.

namespace {

constexpr int T_ = 256;
constexpr int E_ = 64;
constexpr int K2_ = 1020;           // (T-1)*H

typedef float  f32x4  __attribute__((ext_vector_type(4)));
typedef short  bf16x8 __attribute__((ext_vector_type(8)));
typedef unsigned short u16x4 __attribute__((ext_vector_type(4)));

__device__ inline unsigned short f2b(float f) {
    union { float f; unsigned u; } v; v.f = f;
    unsigned r = v.u + 0x7fffu + ((v.u >> 16) & 1u);   // RNE bf16
    return (unsigned short)(r >> 16);
}

__device__ inline bf16x8 pack8(f32x4 a, f32x4 b) {
    bf16x8 r;
    r[0] = (short)f2b(a[0]); r[1] = (short)f2b(a[1]);
    r[2] = (short)f2b(a[2]); r[3] = (short)f2b(a[3]);
    r[4] = (short)f2b(b[0]); r[5] = (short)f2b(b[1]);
    r[6] = (short)f2b(b[2]); r[7] = (short)f2b(b[3]);
    return r;
}

// R4 fallback LDS geometry
constexpr int JC = 4;
constexpr int CHUNKS = 16;
constexpr int W1_ROW   = 72;
constexpr int W1_PLANE = 32 * W1_ROW + 8;
constexpr int PB_ROW   = 24;
constexpr int PB_PLANE = 64 * PB_ROW + 8;
constexpr int W2_ROW   = 16;
constexpr int W2_PLANE = 64 * W2_ROW + 8;

} // namespace

// ======================= shared helpers =======================

// x[b][j][e] f32 -> xT[j][b][e] bf16
__global__ __launch_bounds__(256) void xcast_kernel(
    const float* __restrict__ x, unsigned short* __restrict__ xT)
{
    const int g     = blockIdx.x * 256 + threadIdx.x;   // 262,144
    const int part  = g & 3;                            // 16 e's each
    const int rowid = g >> 2;                           // = b*256 + j
    const int b = rowid >> 8, j = rowid & 255;
    const float* src = x + (size_t)rowid * E_ + part * 16;
    f32x4 v0 = *(const f32x4*)(src);
    f32x4 v1 = *(const f32x4*)(src + 4);
    f32x4 v2 = *(const f32x4*)(src + 8);
    f32x4 v3 = *(const f32x4*)(src + 12);
    unsigned short* dst = xT + ((size_t)j * 256 + b) * E_ + part * 16;
    *(bf16x8*)(dst)     = pack8(v0, v1);
    *(bf16x8*)(dst + 8) = pack8(v2, v3);
}

// out[b,t,e] = b2[t,e] (fallback path only)
__global__ __launch_bounds__(256) void init_out_kernel(
    const float* __restrict__ b2, float* __restrict__ out)
{
    const int idx = blockIdx.x * 256 + threadIdx.x;
    ((f32x4*)out)[idx] = ((const f32x4*)b2)[idx & 4095];
}

// ======================= two-phase path =======================

// W2[t][k][e] f32 -> W2T[t][e][k] bf16 (k-stride padded to 1024)
__global__ __launch_bounds__(512, 2) void w2t_kernel(
    const float* __restrict__ W2, unsigned short* __restrict__ W2T)
{
    __shared__ __align__(16) unsigned short sT[64][136];
    const int bid = blockIdx.x;
    const int t = bid >> 3, kb = bid & 7;               // 8 k-blocks of 128
    const int tid = threadIdx.x;
    {
        const int k  = tid >> 2;            // 0..127
        const int e0 = (tid & 3) << 4;      // 0,16,32,48
        const int kg = kb * 128 + k;
        f32x4 v0 = {0,0,0,0}, v1 = {0,0,0,0}, v2 = {0,0,0,0}, v3 = {0,0,0,0};
        if (kg < K2_) {
            const float* src = W2 + ((size_t)t * K2_ + kg) * E_ + e0;
            v0 = *(const f32x4*)(src);
            v1 = *(const f32x4*)(src + 4);
            v2 = *(const f32x4*)(src + 8);
            v3 = *(const f32x4*)(src + 12);
        }
        #pragma unroll
        for (int m = 0; m < 4; ++m) {
            sT[e0 + m     ][k] = f2b(v0[m]);
            sT[e0 + 4 + m ][k] = f2b(v1[m]);
            sT[e0 + 8 + m ][k] = f2b(v2[m]);
            sT[e0 + 12 + m][k] = f2b(v3[m]);
        }
    }
    __syncthreads();
    {
        const int e  = tid >> 3;            // 0..63
        const int ko = tid & 7;             // 16 k's each
        const unsigned short* srow = &sT[e][ko * 16];
        bf16x8 a = *(const bf16x8*)(srow);
        bf16x8 b = *(const bf16x8*)(srow + 8);
        unsigned short* dst = W2T + ((size_t)t * 64 + e) * 1024 + kb * 128 + ko * 16;
        *(bf16x8*)(dst)     = a;
        *(bf16x8*)(dst + 8) = b;
    }
}

// Phase A v2: grid (32 joct-swz, n_it, 2 bh), 256 threads (4 waves).
// Block: 8 j's x 16 trees x 128 b. Per iq (4 trees): MFMA (m=(il,h), n=b),
// relu+bias -> sH[il][b][k=j*4+h] -> coalesced 64B-row flush to H[i][b][1024k].
__global__ __launch_bounds__(256, 2) void phaseA2_kernel(
    const unsigned short* __restrict__ xT,  // [j][b][e]
    const float* __restrict__ W1,           // [256][256][64][4]
    const float* __restrict__ b1,           // [256][256][4]
    unsigned short* __restrict__ H,         // [TS][256 b][1024 k]
    int i_gbase, int n_it)
{
    __shared__ __align__(16) unsigned short sA[8][16][72];   // [j][m=il*4+h][e] 18.4KB
    __shared__ __align__(16) unsigned short sH[4][128][36];  // [il][b][k]       36.9KB

    // joct swizzle: XCD x (= gid%8) gets joct {4x..4x+3} -> xT slice 1MB L2-resident.
    const int bx   = blockIdx.x;                 // 0..31
    const int joct = (bx & 7) * 4 + (bx >> 3);
    const int it   = blockIdx.y;
    const int bh   = blockIdx.z;
    const int j0   = joct * 8;

    const int tid = threadIdx.x;
    const int w = tid >> 6, lane = tid & 63, r16 = lane & 15, kg = lane >> 4;
    const int bW = w * 32;                       // wave's local b-base (of 128)

    // ---- x fragments, register-resident across all iq (B operand) ----
    bf16x8 xf[8][2][2];
    #pragma unroll
    for (int j = 0; j < 8; ++j)
        #pragma unroll
        for (int nt = 0; nt < 2; ++nt) {
            const unsigned short* xr =
                xT + ((size_t)(j0 + j) * 256 + bh * 128 + bW + nt * 16 + r16) * 64;
            xf[j][nt][0] = *(const bf16x8*)(xr + kg * 8);
            xf[j][nt][1] = *(const bf16x8*)(xr + 32 + kg * 8);
        }

    auto stageA = [&](int iq) {
        const int p = tid >> 3, seg = tid & 7;   // p: il*8+j ; seg: 32 f32 each
        const int il = p >> 3, j = p & 7;
        const int ig = i_gbase + it * 16 + iq * 4 + il;
        const float* src = W1 + ((size_t)ig * 256 + (j0 + j)) * 256 + seg * 32;
        f32x4 v[8];
        #pragma unroll
        for (int s4 = 0; s4 < 8; ++s4) v[s4] = *(const f32x4*)(src + s4 * 4);
        // v[s4][q]: e = seg*8+s4, h = q. Vectorized per-h b128 LDS writes.
        #pragma unroll
        for (int h = 0; h < 4; ++h) {
            bf16x8 pk;
            #pragma unroll
            for (int s4 = 0; s4 < 8; ++s4) pk[s4] = (short)f2b(v[s4][h]);
            *(bf16x8*)&sA[j][il * 4 + h][seg * 8] = pk;
        }
    };

    auto flushH = [&](int iq) {
        #pragma unroll
        for (int half = 0; half < 2; ++half) {
            const int r  = tid + half * 256;     // 512 rows: [il][bl]
            const int il = r >> 7, bl = r & 127;
            const unsigned short* srow = &sH[il][bl][0];
            bf16x8 v0 = *(const bf16x8*)(srow);
            bf16x8 v1 = *(const bf16x8*)(srow + 8);
            bf16x8 v2 = *(const bf16x8*)(srow + 16);
            bf16x8 v3 = *(const bf16x8*)(srow + 24);
            unsigned short* dst =
                H + ((size_t)((it * 16 + iq * 4 + il) * 256 + bh * 128 + bl)) * 1024 + joct * 32;
            *(bf16x8*)(dst)      = v0;
            *(bf16x8*)(dst + 8)  = v1;
            *(bf16x8*)(dst + 16) = v2;
            *(bf16x8*)(dst + 24) = v3;
        }
    };

    for (int iq = 0; iq < 4; ++iq) {
        stageA(iq);
        if (iq > 0) flushH(iq - 1);
        __syncthreads();

        // ---- compute: D[m=(il,h)][n=b] = W1 · x ; lane: il=kg, h=reg, b=nt*16+r16 ----
        #pragma unroll
        for (int j = 0; j < 8; ++j) {
            const unsigned short* ar = &sA[j][r16][0];
            bf16x8 a0 = *(const bf16x8*)(ar + kg * 8);
            bf16x8 a1 = *(const bf16x8*)(ar + 32 + kg * 8);
            const int iS = it * 16 + iq * 4 + kg;          // slice-local tree
            f32x4 bias = *(const f32x4*)(b1 + ((size_t)(i_gbase + iS) * 256 + (j0 + j)) * 4);
            #pragma unroll
            for (int nt = 0; nt < 2; ++nt) {
                f32x4 acc = (f32x4){0.f, 0.f, 0.f, 0.f};
                acc = __builtin_amdgcn_mfma_f32_16x16x32_bf16(a0, xf[j][nt][0], acc, 0, 0, 0);
                acc = __builtin_amdgcn_mfma_f32_16x16x32_bf16(a1, xf[j][nt][1], acc, 0, 0, 0);
                float v0 = acc[0] + bias[0]; v0 = v0 > 0.f ? v0 : 0.f;
                float v1 = acc[1] + bias[1]; v1 = v1 > 0.f ? v1 : 0.f;
                float v2 = acc[2] + bias[2]; v2 = v2 > 0.f ? v2 : 0.f;
                float v3 = acc[3] + bias[3]; v3 = v3 > 0.f ? v3 : 0.f;
                uint2 pk;
                pk.x = (unsigned)f2b(v0) | ((unsigned)f2b(v1) << 16);
                pk.y = (unsigned)f2b(v2) | ((unsigned)f2b(v3) << 16);
                *(uint2*)&sH[kg][bW + nt * 16 + r16][j * 4] = pk;
            }
        }
        __syncthreads();
    }
    flushH(3);
}

// Phase B: block = (tree, b-half). out[b][t][:] = sum_k H2[b][k] W2T[t][:][k] + b2.
__global__ __launch_bounds__(512, 4) void phaseB_kernel(
    const unsigned short* __restrict__ H,    // [TS][256][1024]
    const unsigned short* __restrict__ W2T,  // [256][64][1024]
    const float* __restrict__ b2,            // [256][64]
    float* __restrict__ out,                 // [256][256][64]
    int i_base)
{
    __shared__ __align__(16) unsigned short sA[2][128][72];  // [b][kk] 36.9KB
    __shared__ __align__(16) unsigned short sB[2][64][72];   // [e][kk] 18.4KB

    const int bid = blockIdx.x;
    const int t_loc = bid >> 1;
    const int t  = i_base + t_loc;
    const int b0 = (bid & 1) << 7;
    const int tid = threadIdx.x;
    const int w = tid >> 6, lane = tid & 63, r16 = lane & 15, kg = lane >> 4;

    auto stageA = [&](int c, int pb) {
        const int b = tid >> 2;             // 0..127
        const int q = tid & 3;              // 32B each
        const unsigned short* src =
            H + ((size_t)t_loc << 18) + ((size_t)(b0 + b) << 10) + (c << 6) + (q << 4);
        bf16x8 v0 = *(const bf16x8*)(src);
        bf16x8 v1 = *(const bf16x8*)(src + 8);
        *(bf16x8*)&sA[pb][b][(q << 4)]     = v0;
        *(bf16x8*)&sA[pb][b][(q << 4) + 8] = v1;
    };
    auto stageB = [&](int c, int pb) {
        const int e   = tid >> 3;           // 0..63
        const int grp = tid & 7;            // 2 j's each
        const unsigned short* base = W2T + ((size_t)t * 64 + e) * 1024;
        #pragma unroll
        for (int js = 0; js < 2; ++js) {
            const int jj = grp * 2 + js;    // 0..15
            const int j  = c * 16 + jj;
            u16x4 v;
            if (j == t) {
                v = (u16x4){0, 0, 0, 0};
            } else {
                const int ks = ((j < t) ? j : j - 1) << 2;
                v = *(const u16x4*)(base + ks);
            }
            *(u16x4*)&sB[pb][e][jj << 2] = v;
        }
    };

    stageA(0, 0); stageB(0, 0);
    __syncthreads();

    f32x4 acc[4];
    #pragma unroll
    for (int nt = 0; nt < 4; ++nt) acc[nt] = (f32x4){0.f, 0.f, 0.f, 0.f};

    for (int c = 0; c < 16; ++c) {
        const int pb = c & 1;
        if (c + 1 < 16) { stageA(c + 1, pb ^ 1); stageB(c + 1, pb ^ 1); }

        const unsigned short* ar = &sA[pb][w * 16 + r16][0];
        bf16x8 a0 = *(const bf16x8*)(ar + kg * 8);
        bf16x8 a1 = *(const bf16x8*)(ar + 32 + kg * 8);
        #pragma unroll
        for (int nt = 0; nt < 4; ++nt) {
            const unsigned short* br = &sB[pb][nt * 16 + r16][0];
            bf16x8 bb0 = *(const bf16x8*)(br + kg * 8);
            bf16x8 bb1 = *(const bf16x8*)(br + 32 + kg * 8);
            acc[nt] = __builtin_amdgcn_mfma_f32_16x16x32_bf16(a0, bb0, acc[nt], 0, 0, 0);
            acc[nt] = __builtin_amdgcn_mfma_f32_16x16x32_bf16(a1, bb1, acc[nt], 0, 0, 0);
        }
        __syncthreads();
    }

    #pragma unroll
    for (int nt = 0; nt < 4; ++nt) {
        const int e = nt * 16 + r16;
        const float bias = b2[(t << 6) + e];
        #pragma unroll
        for (int r = 0; r < 4; ++r) {
            const int b = b0 + w * 16 + kg * 4 + r;
            out[((size_t)b << 14) + (t << 6) + e] = acc[nt][r] + bias;
        }
    }
}

// ======================= fallback: R4 monolithic fused kernel =======================

template <bool XBF>
__global__ __launch_bounds__(512, 4) void fused_forest_kernel(
    const void*  __restrict__ xv,
    const float* __restrict__ W1,
    const float* __restrict__ b1,
    const float* __restrict__ W2,
    float* __restrict__ out)
{
    __shared__ __align__(16) unsigned short sW1[4 * W1_PLANE];
    __shared__ __align__(16) unsigned short sPB[8 * PB_PLANE];
    __shared__ __align__(16) unsigned short sW2[2][8 * W2_PLANE];
    __shared__ __align__(16) float sB1[4][32];

    const int bid = blockIdx.x;
    const int xcd = bid & 7;
    const int rr  = bid >> 3;
    const int tgl = rr >> 4;
    const int bg  = (rr >> 2) & 3;
    const int jg  = rr & 3;
    const int tg  = tgl * 8 + xcd;
    const int i0  = tg << 3;
    const int b0  = bg << 6;
    const int j0g = jg << 6;

    const int tid  = threadIdx.x;
    const int w    = tid >> 6;
    const int lane = tid & 63;
    const int r16  = lane & 15;
    const int kg   = lane >> 4;
    const int bt   = w & 3;
    const int mh   = w >> 2;

    f32x4 acc[4][4];
    #pragma unroll
    for (int mt = 0; mt < 4; ++mt)
        #pragma unroll
        for (int nt = 0; nt < 4; ++nt)
            acc[mt][nt] = (f32x4){0.f, 0.f, 0.f, 0.f};

    auto stage = [&](int c, int pb) {
        const int j0 = j0g + c * JC;
        if (tid < 128) {
            const int jj = tid >> 5, ih = tid & 31;
            sB1[jj][ih] = b1[((i0 + (ih >> 2)) * T_ + (j0 + jj)) * 4 + (ih & 3)];
        }
        {
            const float* src = W1 + (((size_t)(i0 + w) * T_ + (j0 + kg)) * E_) * 4 + r16 * 16;
            f32x4 v0 = *(const f32x4*)(src);
            f32x4 v1 = *(const f32x4*)(src + 4);
            f32x4 v2 = *(const f32x4*)(src + 8);
            f32x4 v3 = *(const f32x4*)(src + 12);
            #pragma unroll
            for (int h = 0; h < 4; ++h) {
                u16x4 pk = (u16x4){f2b(v0[h]), f2b(v1[h]), f2b(v2[h]), f2b(v3[h])};
                *(u16x4*)&sW1[kg * W1_PLANE + (w * 4 + h) * W1_ROW + r16 * 4] = pk;
            }
        }
        {
            const int kk   = lane >> 2;
            const int e0   = (lane & 3) * 16;
            const int tabs = i0 + w;
            const int j    = j0 + (kk >> 2);
            unsigned short* dst = &sW2[pb][w * W2_PLANE + kk];
            if (j == tabs) {
                #pragma unroll
                for (int q = 0; q < 16; ++q) dst[(e0 + q) * W2_ROW] = 0;
            } else {
                const int ksrc = ((j < tabs) ? j : j - 1) * 4 + (kk & 3);
                const float* src = W2 + ((size_t)tabs * K2_ + ksrc) * E_ + e0;
                f32x4 v0 = *(const f32x4*)(src);
                f32x4 v1 = *(const f32x4*)(src + 4);
                f32x4 v2 = *(const f32x4*)(src + 8);
                f32x4 v3 = *(const f32x4*)(src + 12);
                #pragma unroll
                for (int q = 0; q < 4; ++q) {
                    dst[(e0 + q)      * W2_ROW] = f2b(v0[q]);
                    dst[(e0 + 4 + q)  * W2_ROW] = f2b(v1[q]);
                    dst[(e0 + 8 + q)  * W2_ROW] = f2b(v2[q]);
                    dst[(e0 + 12 + q) * W2_ROW] = f2b(v3[q]);
                }
            }
        }
    };

    stage(0, 0);
    __syncthreads();

    const int brow = b0 + bt * 16 + r16;

    for (int c = 0; c < CHUNKS; ++c) {
        const int j0 = j0g + c * JC;
        #pragma unroll
        for (int jj = 0; jj < JC; ++jj) {
            bf16x8 xa, xc;
            if (XBF) {
                const unsigned short* xr =
                    (const unsigned short*)xv + ((size_t)(j0 + jj) * 256 + brow) * E_;
                xa = *(const bf16x8*)(xr + kg * 8);
                xc = *(const bf16x8*)(xr + 32 + kg * 8);
            } else {
                const float* xr = (const float*)xv + ((size_t)brow * T_ + (j0 + jj)) * E_ + kg * 8;
                xa = pack8(*(const f32x4*)xr, *(const f32x4*)(xr + 4));
                xc = pack8(*(const f32x4*)(xr + 32), *(const f32x4*)(xr + 36));
            }
            const unsigned short* wr = &sW1[jj * W1_PLANE + (mh * 16 + r16) * W1_ROW];
            bf16x8 wa = *(const bf16x8*)(wr + kg * 8);
            bf16x8 wc = *(const bf16x8*)(wr + 32 + kg * 8);
            f32x4 cf = (f32x4){0.f, 0.f, 0.f, 0.f};
            cf = __builtin_amdgcn_mfma_f32_16x16x32_bf16(wa, xa, cf, 0, 0, 0);
            cf = __builtin_amdgcn_mfma_f32_16x16x32_bf16(wc, xc, cf, 0, 0, 0);
            const int i = mh * 4 + kg;
            f32x4 bias = *(const f32x4*)&sB1[jj][i * 4];
            #pragma unroll
            for (int r = 0; r < 4; ++r) {
                float vv = cf[r] + bias[r];
                cf[r] = vv > 0.f ? vv : 0.f;
            }
            unsigned p0 = (unsigned)f2b(cf[0]) | ((unsigned)f2b(cf[1]) << 16);
            unsigned p1 = (unsigned)f2b(cf[2]) | ((unsigned)f2b(cf[3]) << 16);
            uint2 pk; pk.x = p0; pk.y = p1;
            *(uint2*)&sPB[i * PB_PLANE + (bt * 16 + r16) * PB_ROW + jj * 4] = pk;
        }
        __syncthreads();

        {
            const bf16x8 z = (bf16x8){0,0,0,0,0,0,0,0};
            const bool lo = (kg < 2);
            bf16x8 a2[4], bb[4];
            #pragma unroll
            for (int mt = 0; mt < 4; ++mt)
                a2[mt] = lo ? *(const bf16x8*)&sPB[w * PB_PLANE + (mt * 16 + r16) * PB_ROW + kg * 8] : z;
            #pragma unroll
            for (int nt = 0; nt < 4; ++nt)
                bb[nt] = lo ? *(const bf16x8*)&sW2[c & 1][w * W2_PLANE + (nt * 16 + r16) * W2_ROW + kg * 8] : z;
            #pragma unroll
            for (int mt = 0; mt < 4; ++mt)
                #pragma unroll
                for (int nt = 0; nt < 4; ++nt)
                    acc[mt][nt] = __builtin_amdgcn_mfma_f32_16x16x32_bf16(
                        a2[mt], bb[nt], acc[mt][nt], 0, 0, 0);
        }

        if (c + 1 < CHUNKS) stage(c + 1, (c + 1) & 1);
        __syncthreads();
    }

    const int tabs = i0 + w;
    #pragma unroll
    for (int mt = 0; mt < 4; ++mt) {
        const int b = b0 + mt * 16 + kg * 4;
        #pragma unroll
        for (int nt = 0; nt < 4; ++nt) {
            const int e = nt * 16 + r16;
            #pragma unroll
            for (int r = 0; r < 4; ++r)
                unsafeAtomicAdd(&out[((size_t)(b + r) * T_ + tabs) * E_ + e],
                                acc[mt][nt][r]);
        }
    }
}

// ======================= host =======================

extern "C" void kernel_launch(void* const* d_in, const int* in_sizes, int n_in,
                              void* d_out, int out_size, void* d_ws, size_t ws_size,
                              hipStream_t stream) {
    const float* x  = (const float*)d_in[0];
    const float* W1 = (const float*)d_in[1];
    const float* b1 = (const float*)d_in[2];
    const float* W2 = (const float*)d_in[3];
    const float* b2 = (const float*)d_in[4];
    float* out = (float*)d_out;
    (void)in_sizes; (void)n_in; (void)out_size;

    const size_t xT_b   = 8388608ull;     // 256*256*64*2
    const size_t w2t_b  = 33554432ull;    // 256*64*1024*2
    const size_t H_full = 134217728ull;   // 256*256*1024*2

    int NS = 0;
    if (d_ws) {
        const int cands[4] = {1, 2, 4, 8};
        for (int ci = 0; ci < 4; ++ci) {
            if (ws_size >= xT_b + w2t_b + H_full / cands[ci]) { NS = cands[ci]; break; }
        }
    }

    if (NS) {
        unsigned short* xT  = (unsigned short*)d_ws;
        unsigned short* W2T = (unsigned short*)((char*)d_ws + xT_b);
        unsigned short* H   = (unsigned short*)((char*)d_ws + xT_b + w2t_b);

        hipLaunchKernelGGL(xcast_kernel, dim3(1024), dim3(256), 0, stream, x, xT);
        hipLaunchKernelGGL(w2t_kernel, dim3(2048), dim3(512), 0, stream, W2, W2T);

        const int TS = 256 / NS;
        const int n_it = TS / 16;
        for (int s = 0; s < NS; ++s) {
            hipLaunchKernelGGL(phaseA2_kernel, dim3(32, n_it, 2), dim3(256), 0, stream,
                               xT, W1, b1, H, s * TS, n_it);
            hipLaunchKernelGGL(phaseB_kernel, dim3(TS * 2), dim3(512), 0, stream,
                               H, W2T, b2, out, s * TS);
        }
    } else {
        const bool xbf = d_ws && ws_size >= xT_b;
        hipLaunchKernelGGL(init_out_kernel, dim3(4096), dim3(256), 0, stream, b2, out);
        if (xbf) {
            hipLaunchKernelGGL(xcast_kernel, dim3(1024), dim3(256), 0, stream,
                               x, (unsigned short*)d_ws);
            hipLaunchKernelGGL(fused_forest_kernel<true>, dim3(512), dim3(512), 0, stream,
                               (const void*)d_ws, W1, b1, W2, out);
        } else {
            hipLaunchKernelGGL(fused_forest_kernel<false>, dim3(512), dim3(512), 0, stream,
                               (const void*)x, W1, b1, W2, out);
        }
    }
}